// Round 13
// baseline (445.700 us; speedup 1.0000x reference)
//
#include <hip/hip_runtime.h>

// Conv1dFFTInt8: B=16, CIN=128, COUT=128, L=4096, out_size==1.
// Identity: ifft(sum_l X[l]W[l])[0] = sum_n x[n] * w[(L-n) mod L]  (real inputs)
// => out[b,o] = bias[o] + sum_i sum_m w[o,i,m] * x[b,i,(L-m)&(L-1)]
//
// R4-R12: every register-prefetch schedule lands at ~2.6 TB/s effective weight
// stream. Falsified: lockstep, hotspot, atomics, x-restage, LDS-unit. Last
// standing theory: per-CU outstanding-bytes sawtooth to ~0 each phase (weight
// loads issued <=300cyc before use; vmcnt kept only 4-8 KB across barriers) ->
// queue drain/refill, effective latency ~8000cyc by Little's law.
// This round: weights staged through LDS (global_load_lds = ZERO VGPR cost,
// the R7 killer removed), TRI-buffered (u,u+1,u+2): a constant >=32KB/CU in
// flight across every barrier via counted vmcnt(33); drains to 0 only in the
// epilogue. Read-once skeleton kept (x staged once, 32MB machine-wide;
// weights 268MB once; ws split-K + reduce kernel). LDS 144KB -> 1 block/CU
// (BW-bound by design; in-flight depth no longer depends on TLP).

constexpr int LEN   = 4096;
constexpr int CIN_  = 128;
constexpr int COUT_ = 128;
constexpr int BATCH = 16;

typedef float f32x4 __attribute__((ext_vector_type(4)));

__global__ void init_out_kernel(const float* __restrict__ bias, float* __restrict__ out) {
    int t = blockIdx.x * 256 + threadIdx.x;
    if (t < BATCH * COUT_) out[t] = bias[t & (COUT_ - 1)];
}

// Async 4B global->LDS. LDS dest is wave-uniform base (+lane*4 in HW);
// per-lane global source carries any reversal/offset.
__device__ __forceinline__ void gload_lds4(const float* g, float* l) {
    __builtin_amdgcn_global_load_lds(
        (const __attribute__((address_space(1))) unsigned int*)g,
        (__attribute__((address_space(3))) unsigned int*)l, 4, 0, 0);
}

// Quad (4-lane) sum on the VALU pipe via DPP quad_perm — zero LDS-unit cost.
__device__ __forceinline__ float quad_sum(float v) {
    v += __int_as_float(__builtin_amdgcn_update_dpp(
            0, __float_as_int(v), 0xB1, 0xF, 0xF, true));   // quad_perm(1,0,3,2)
    v += __int_as_float(__builtin_amdgcn_update_dpp(
            0, __float_as_int(v), 0x4E, 0xF, 0xF, true));   // quad_perm(2,3,0,1)
    return v;
}

// Stage unit U's 16 weight rows (512-float slices) into wls buffer BUF.
// Wave wv stages its own compute rows 4wv..4wv+3. 32 gload_lds4 per wave.
#define WSTAGE(U, BUF)                                                        \
    {                                                                         \
        _Pragma("unroll")                                                     \
        for (int rr = 0; rr < 4; ++rr) {                                      \
            const int row = ((U) << 4) + 4 * wv + rr;                         \
            const float* src = w + (((row << 7) + ci) << 12) + m0;            \
            float* dst = wls + ((BUF) << 13) + ((4 * wv + rr) << 9);          \
            _Pragma("unroll")                                                 \
            for (int t = 0; t < 8; ++t)                                       \
                gload_lds4(src + (t << 6) + lane, dst + (t << 6));            \
        }                                                                     \
    }

// Block: 256 threads = 4 waves. Owns (ci, msplit): all 128 o for one
// 512-float m-slice, in 8 units of 16 o. Grid = 8 msplit * 128 ci = 1024.
// Partials -> ws[bk][b*128+o] (8MB), summed by reduce_ws_kernel.
__global__ __launch_bounds__(256, 2)
void conv_partial_kernel(const float* __restrict__ x, const float* __restrict__ w,
                         float* __restrict__ ws) {
    __shared__ float xls[8192];       // 32 KB: x slice, staged once
    __shared__ float wls[3 * 8192];   // 96 KB: tri-buffered weight pipeline
    __shared__ float fl[4096];        // 16 KB: 4 wave-private flush pads

    const int tid  = threadIdx.x;
    const int lane = tid & 63;
    const int wv   = __builtin_amdgcn_readfirstlane(tid >> 6);
    const int bk   = blockIdx.x;
    const int ms   = bk >> 7;          // m-split 0..7
    const int ci   = bk & 127;         // input channel
    const int m0   = ms << 9;

    // ---- prologue: x (once) + weight units 0,1. Order pinned; keep unit-1
    // in flight across the barrier (vmcnt(32)).
#pragma unroll
    for (int bb = 0; bb < 4; ++bb) {
        const int b = 4 * wv + bb;
        const float* xc = x + ((b * CIN_ + ci) << 12);
        float* dst = xls + (b << 9);
#pragma unroll
        for (int t = 0; t < 8; ++t) {
            const int n = (LEN - m0 - (t << 6) - lane) & (LEN - 1);  // reversed src
            gload_lds4(xc + n, dst + (t << 6));
        }
    }
    __builtin_amdgcn_sched_barrier(0);
    WSTAGE(0, 0)
    __builtin_amdgcn_sched_barrier(0);
    WSTAGE(1, 1)
    __builtin_amdgcn_sched_barrier(0);
    asm volatile("s_waitcnt vmcnt(32)" ::: "memory");  // x+unit0 done; unit1 in flight
    __builtin_amdgcn_s_barrier();
    __builtin_amdgcn_sched_barrier(0);

    float acc[16][4];
#pragma unroll
    for (int b = 0; b < 16; ++b)
#pragma unroll
        for (int j = 0; j < 4; ++j) acc[b][j] = 0.f;

    const float4* xls4 = (const float4*)xls;
    float* fr  = fl + (wv << 10);           // wave-private 1024-float pad
    float* wsb = ws + (size_t)bk * 2048;    // block-private partial slab
    const int q  = lane >> 2;               // quad id 0..15 (= b in flush)
    const int jo = lane & 3;                // o-sublane 0..3

#pragma unroll 1
    for (int u = 0; u < 8; ++u) {
        // ---- (a) issue stage(u+2): keeps >=32KB/CU in flight through the
        // barrier below. Tri-buffer: never overwrites a live buffer.
        if (u < 6) WSTAGE(u + 2, (u + 2) % 3)
        __builtin_amdgcn_sched_barrier(0);

        // ---- (b) compute unit u from wls[u%3]: 8 ds_read_b128 of weights
        // (reused over 16 b) + 32 of x; 512 FMAs.
        const f32x4* wb4 = (const f32x4*)(wls + ((u % 3) << 13));
        f32x4 wcv[8];
#pragma unroll
        for (int j = 0; j < 4; ++j) {
            wcv[j]     = wb4[((4 * wv + j) << 7) + lane];
            wcv[4 + j] = wb4[((4 * wv + j) << 7) + 64 + lane];
        }
#pragma unroll
        for (int b = 0; b < 16; ++b) {
            const float4 xv0 = xls4[(b << 7) + lane];
            const float4 xv1 = xls4[(b << 7) + 64 + lane];
#pragma unroll
            for (int j = 0; j < 4; ++j) {
                acc[b][j] += xv0.x * wcv[j].x + xv0.y * wcv[j].y
                           + xv0.z * wcv[j].z + xv0.w * wcv[j].w;
                acc[b][j] += xv1.x * wcv[4 + j].x + xv1.y * wcv[4 + j].y
                           + xv1.z * wcv[4 + j].z + xv1.w * wcv[4 + j].w;
            }
        }

        // ---- (c) flush: DPP quad-reduce -> 16+16 b32 DS ops -> 1 ws store.
        // All acc indices static (rule #20); u enters addresses only.
#pragma unroll
        for (int b = 0; b < 16; ++b) {
            const float qs0 = quad_sum(acc[b][0]);
            const float qs1 = quad_sum(acc[b][1]);
            const float qs2 = quad_sum(acc[b][2]);
            const float qs3 = quad_sum(acc[b][3]);
            const float v = (jo == 0) ? qs0 : (jo == 1) ? qs1
                          : (jo == 2) ? qs2 : qs3;
            fr[(b << 6) + ((q ^ b) << 2) + jo] = v;
            acc[b][0] = 0.f; acc[b][1] = 0.f; acc[b][2] = 0.f; acc[b][3] = 0.f;
        }
        {
            float s = 0.f;
#pragma unroll
            for (int k = 0; k < 16; ++k)
                s += fr[(q << 6) + ((k ^ q) << 2) + jo];
            wsb[(q << 7) + u * 16 + wv * 4 + jo] = s;
        }

        // ---- (d) counted barrier: wait stage(u+1) complete, keep stage(u+2)
        // (32 loads) + this u's ws store (1) in flight => vmcnt(33).
        if (u < 6) {
            asm volatile("s_waitcnt vmcnt(33)" ::: "memory");
            __builtin_amdgcn_s_barrier();
            __builtin_amdgcn_sched_barrier(0);
        } else if (u == 6) {
            asm volatile("s_waitcnt vmcnt(1)" ::: "memory");  // drain stage(7)
            __builtin_amdgcn_s_barrier();
            __builtin_amdgcn_sched_barrier(0);
        }
    }
}

// Reduce: out[bo] += sum_s ws[s][bo].  Grid 64 = 8 bo-chunks x 8 s-chunks;
// threads adjacent in bo -> every load coalesced. Atomic fan-in 8 (trivial).
__global__ __launch_bounds__(256, 4)
void reduce_ws_kernel(const float* __restrict__ ws, float* __restrict__ out) {
    const int bo = ((blockIdx.x & 7) << 8) + threadIdx.x;
    const int s0 = (blockIdx.x >> 3) << 7;
    const float* p = ws + (size_t)s0 * 2048 + bo;
    float s = 0.f;
#pragma unroll 8
    for (int i = 0; i < 128; ++i) s += p[(size_t)i * 2048];
    atomicAdd(out + bo, s);
}

extern "C" void kernel_launch(void* const* d_in, const int* in_sizes, int n_in,
                              void* d_out, int out_size, void* d_ws, size_t ws_size,
                              hipStream_t stream) {
    const float* x    = (const float*)d_in[0];   // [16,128,4096]
    const float* wgt  = (const float*)d_in[1];   // [128,128,4096]
    const float* bias = (const float*)d_in[2];   // [128]
    float* out = (float*)d_out;                  // [16,128,1]
    float* ws  = (float*)d_ws;                   // >= 8 MB workspace
    (void)in_sizes; (void)n_in; (void)ws_size; (void)out_size;

    init_out_kernel<<<8, 256, 0, stream>>>(bias, out);
    conv_partial_kernel<<<1024, 256, 0, stream>>>(x, wgt, ws);
    reduce_ws_kernel<<<64, 256, 0, stream>>>(ws, out);
}

// Round 15
// 401.174 us; speedup vs baseline: 1.1110x; 1.1110x over previous
//
#include <hip/hip_runtime.h>

// Conv1dFFTInt8: B=16, CIN=128, COUT=128, L=4096, out_size==1.
// Identity: ifft(sum_l X[l]W[l])[0] = sum_n x[n] * w[(L-n) mod L]  (real inputs)
// => out[b,o] = bias[o] + sum_i sum_m w[o,i,m] * x[b,i,(L-m)&(L-1)]
//
// (Resubmission of R14 — the bench container failed; no kernel verdict.)
// 13-round synthesis: need BOTH wave-overlap AND >=1-latency load cover.
// R8: 16 waves/CU but barrier-drained in-flight (~106us). R11: no barriers
// but only ~300cyc cover -> per-unit stall (~108us). R13: cover but 1
// wave/SIMD (170us). This round: read-once skeleton (R11) + 512-thr blocks,
// wave owns 2 o-rows/unit -> acc[16][2]=32 VGPR frees room for 2-UNIT-deep
// ping-pong weight prefetch (wcA/wcB, ~7000cyc cover). 48KB LDS -> 2
// blocks/CU = 16 waves/CU, ~100KB/CU sustained in flight. No main-loop
// barriers, no manual vmcnt (compiler's counted waits are precise); fences
// only pin unit order (prevents whole-kernel load hoist = R7 spill mode).

constexpr int LEN   = 4096;
constexpr int CIN_  = 128;
constexpr int COUT_ = 128;
constexpr int BATCH = 16;

typedef float f32x4 __attribute__((ext_vector_type(4)));

__global__ void init_out_kernel(const float* __restrict__ bias, float* __restrict__ out) {
    int t = blockIdx.x * 256 + threadIdx.x;
    if (t < BATCH * COUT_) out[t] = bias[t & (COUT_ - 1)];
}

// Non-temporal 16B weight load: read-once stream.
__device__ __forceinline__ f32x4 ntload4(const float* p) {
    return __builtin_nontemporal_load((const f32x4*)p);
}

// Async 4B global->LDS. LDS dest = wave-uniform base + lane*4 (HW);
// per-lane global source carries the reversal.
__device__ __forceinline__ void gload_lds4(const float* g, float* l) {
    __builtin_amdgcn_global_load_lds(
        (const __attribute__((address_space(1))) unsigned int*)g,
        (__attribute__((address_space(3))) unsigned int*)l, 4, 0, 0);
}

// Quad (4-lane) sum on the VALU pipe via DPP quad_perm (validated R12).
__device__ __forceinline__ float quad_sum(float v) {
    v += __int_as_float(__builtin_amdgcn_update_dpp(
            0, __float_as_int(v), 0xB1, 0xF, 0xF, true));   // quad_perm(1,0,3,2)
    v += __int_as_float(__builtin_amdgcn_update_dpp(
            0, __float_as_int(v), 0x4E, 0xF, 0xF, true));   // quad_perm(2,3,0,1)
    return v;
}

// Load this wave's 2 weight rows of unit U (rows 16U+2wv, +1; 2 quads each).
// o-row stride in w = CIN_*LEN = 1<<19 floats.
#define WLOAD(WC, U)                                                          \
    {                                                                         \
        const float* wr_ = w + ((((16 * (U) + 2 * wv) << 7) + ci) << 12) + m0;\
        WC[0] = ntload4(wr_ + lo);                                            \
        WC[1] = ntload4(wr_ + 256 + lo);                                      \
        WC[2] = ntload4(wr_ + (1 << 19) + lo);          /* next o-row */      \
        WC[3] = ntload4(wr_ + (1 << 19) + 256 + lo);                          \
    }

// One unit: compute 16b x 2o from WC (loaded 2 units ago), reload WC for
// U+2, flush acc via DPP quad-reduce + tiny wave-private LDS transpose.
// All acc/WC indices static (rule #20); U is a literal.
#define UNIT(U, WC, ISSUE)                                                    \
    {                                                                         \
        __builtin_amdgcn_sched_barrier(0);                                    \
        _Pragma("unroll")                                                     \
        for (int b = 0; b < 16; ++b) {                                        \
            const float4 xv0 = xls4[(b << 7) + lane];                         \
            const float4 xv1 = xls4[(b << 7) + 64 + lane];                    \
            acc[b][0] += xv0.x * WC[0].x + xv0.y * WC[0].y                    \
                       + xv0.z * WC[0].z + xv0.w * WC[0].w;                   \
            acc[b][0] += xv1.x * WC[1].x + xv1.y * WC[1].y                    \
                       + xv1.z * WC[1].z + xv1.w * WC[1].w;                   \
            acc[b][1] += xv0.x * WC[2].x + xv0.y * WC[2].y                    \
                       + xv0.z * WC[2].z + xv0.w * WC[2].w;                   \
            acc[b][1] += xv1.x * WC[3].x + xv1.y * WC[3].y                    \
                       + xv1.z * WC[3].z + xv1.w * WC[3].w;                   \
        }                                                                     \
        __builtin_amdgcn_sched_barrier(0);                                    \
        if (ISSUE) WLOAD(WC, (U) + 2)                                         \
        __builtin_amdgcn_sched_barrier(0);                                    \
        _Pragma("unroll")                                                     \
        for (int b = 0; b < 16; ++b) {                                        \
            const float qs0 = quad_sum(acc[b][0]);                            \
            const float qs1 = quad_sum(acc[b][1]);                            \
            if (jo < 2)                                                       \
                fr[(b << 5) + ((q ^ b) << 1) + jo] = (jo == 0) ? qs0 : qs1;   \
            acc[b][0] = 0.f; acc[b][1] = 0.f;                                 \
        }                                                                     \
        if (lane < 32) {                                                      \
            const int b_ = lane >> 1, j_ = lane & 1;                          \
            float s = 0.f;                                                    \
            _Pragma("unroll")                                                 \
            for (int k = 0; k < 16; ++k)                                      \
                s += fr[(b_ << 5) + ((k ^ b_) << 1) + j_];                    \
            wsb[(b_ << 7) + 16 * (U) + 2 * wv + j_] = s;                      \
        }                                                                     \
    }

// Block: 512 threads = 8 waves. Owns (ci, msplit): all 128 o for one
// 512-float m-slice, 8 units of 16 o-rows; wave wv computes rows
// {16u+2wv, 16u+2wv+1}. Grid = 8 msplit * 128 ci = 1024 blocks.
// Partials -> ws[bk][b*128+o] (8MB), summed by reduce_ws_kernel.
// __launch_bounds__(512,2): empirical VGPR cap 128 -> 2 blocks/CU.
__global__ __launch_bounds__(512, 2)
void conv_partial_kernel(const float* __restrict__ x, const float* __restrict__ w,
                         float* __restrict__ ws) {
    __shared__ float xls[8192];   // 32 KB: x slice, staged once
    __shared__ float fl[4096];    // 16 KB: 8 wave-private 512-float flush pads

    const int tid  = threadIdx.x;
    const int lane = tid & 63;
    const int wv   = __builtin_amdgcn_readfirstlane(tid >> 6);  // 0..7
    const int bk   = blockIdx.x;
    const int ms   = bk >> 7;          // m-split 0..7
    const int ci   = bk & 127;         // input channel
    const int m0   = ms << 9;
    const int lo   = lane << 2;        // float offset of lane's quad

    // ---- one-time x stage: wave wv stages batches {2wv, 2wv+1} (reversed src)
#pragma unroll
    for (int bb = 0; bb < 2; ++bb) {
        const int b = 2 * wv + bb;
        const float* xc = x + ((b * CIN_ + ci) << 12);
        float* dst = xls + (b << 9);
#pragma unroll
        for (int t = 0; t < 8; ++t) {
            const int n = (LEN - m0 - (t << 6) - lane) & (LEN - 1);
            gload_lds4(xc + n, dst + (t << 6));
        }
    }
    __builtin_amdgcn_sched_barrier(0);

    f32x4 wcA[4], wcB[4];
    WLOAD(wcA, 0)
    WLOAD(wcB, 1)
    __syncthreads();   // full drain once; x visible block-wide

    float acc[16][2];
#pragma unroll
    for (int b = 0; b < 16; ++b) { acc[b][0] = 0.f; acc[b][1] = 0.f; }

    const float4* xls4 = (const float4*)xls;
    float* fr  = fl + (wv << 9);            // wave-private 512-float pad
    float* wsb = ws + (size_t)bk * 2048;    // block-private partial slab
    const int q  = lane >> 2;               // quad id 0..15
    const int jo = lane & 3;

    // ---- 8 units, fully static; wcA serves even units, wcB odd; each unit
    // reloads its register set for unit+2 (2-unit pipeline depth).
    UNIT(0, wcA, 1)
    UNIT(1, wcB, 1)
    UNIT(2, wcA, 1)
    UNIT(3, wcB, 1)
    UNIT(4, wcA, 1)
    UNIT(5, wcB, 1)
    UNIT(6, wcA, 0)
    UNIT(7, wcB, 0)
}

// Reduce: out[bo] += sum_s ws[s][bo].  Grid 64 = 8 bo-chunks x 8 s-chunks;
// threads adjacent in bo -> coalesced. Atomic fan-in 8 (trivial).
__global__ __launch_bounds__(256, 4)
void reduce_ws_kernel(const float* __restrict__ ws, float* __restrict__ out) {
    const int bo = ((blockIdx.x & 7) << 8) + threadIdx.x;
    const int s0 = (blockIdx.x >> 3) << 7;
    const float* p = ws + (size_t)s0 * 2048 + bo;
    float s = 0.f;
#pragma unroll 8
    for (int i = 0; i < 128; ++i) s += p[(size_t)i * 2048];
    atomicAdd(out + bo, s);
}

extern "C" void kernel_launch(void* const* d_in, const int* in_sizes, int n_in,
                              void* d_out, int out_size, void* d_ws, size_t ws_size,
                              hipStream_t stream) {
    const float* x    = (const float*)d_in[0];   // [16,128,4096]
    const float* wgt  = (const float*)d_in[1];   // [128,128,4096]
    const float* bias = (const float*)d_in[2];   // [128]
    float* out = (float*)d_out;                  // [16,128,1]
    float* ws  = (float*)d_ws;                   // >= 8 MB workspace
    (void)in_sizes; (void)n_in; (void)ws_size; (void)out_size;

    init_out_kernel<<<8, 256, 0, stream>>>(bias, out);
    conv_partial_kernel<<<1024, 512, 0, stream>>>(x, wgt, ws);
    reduce_ws_kernel<<<64, 256, 0, stream>>>(ws, out);
}

// Round 16
// 372.112 us; speedup vs baseline: 1.1978x; 1.0781x over previous
//
#include <hip/hip_runtime.h>

// Conv1dFFTInt8: B=16, CIN=128, COUT=128, L=4096, out_size==1.
// Identity: ifft(sum_l X[l]W[l])[0] = sum_n x[n] * w[(L-n) mod L]  (real inputs)
// => out[b,o] = bias[o] + sum_i sum_m w[o,i,m] * x[b,i,(L-m)&(L-1)]
//
// FINAL (session best, R8: 372.7us measured; conv ~106us vs ~48us HBM floor,
// ~267us of dur_us is harness-fixed fill).
// Structure: 256-thread blocks (4 waves, 4 o-rows/wave = o-tile 16), ONE input
// channel per block, 16 K-chunks of 256 floats, x double-buffered in 32KB LDS
// via global_load_lds with per-lane REVERSED global source (LDS stays linear),
// non-temporal weight loads, counted vmcnt(4) barriers (next-chunk weight
// loads stay in flight), 4 blocks/CU. Epilogue: padded LDS transpose, fully
// static indices (rule #20), atomic fan-in 128/address (hidden).
// Falsified levers for the remaining 2x: lockstep TLP, chunk-phase rotation,
// atomic stalls, x-restage traffic, LDS-unit serialization, in-flight depth
// (LDS tri-buffer AND 2-deep register ping-pong). All land at 105-135us.
// Residual hypothesis (untested): DRAM page locality of the 16KB-strided
// read-once weight stream; would require contiguous per-block weight regions.

constexpr int LEN   = 4096;
constexpr int CIN_  = 128;
constexpr int COUT_ = 128;
constexpr int BATCH = 16;

typedef float f32x4 __attribute__((ext_vector_type(4)));

__global__ void init_out_kernel(const float* __restrict__ bias, float* __restrict__ out) {
    int t = blockIdx.x * 256 + threadIdx.x;
    if (t < BATCH * COUT_) out[t] = bias[t & (COUT_ - 1)];
}

// Non-temporal 16B weight load: read-once stream, keep L2 for x.
__device__ __forceinline__ f32x4 ntload4(const float* p) {
    return __builtin_nontemporal_load((const f32x4*)p);
}

// Async 4B global->LDS. LDS dest is wave-uniform base (+lane*4 in HW);
// the index reversal lives in the per-lane GLOBAL address.
__device__ __forceinline__ void gload_lds4(const float* g, float* l) {
    __builtin_amdgcn_global_load_lds(
        (const __attribute__((address_space(1))) unsigned int*)g,
        (__attribute__((address_space(3))) unsigned int*)l, 4, 0, 0);
}

// Wave wv stages batches 4wv..4wv+3 for one 256-float chunk at m0:
// buf[b*256 + u] = x[b, ci, (LEN - m0 - u) & 4095], u in [0,256). 16 gloads.
#define STAGE(BUF, M0)                                                     \
    {                                                                      \
        _Pragma("unroll")                                                  \
        for (int t = 0; t < 4; ++t) {                                      \
            const int n = (LEN - (M0) - (t << 6) - lane) & (LEN - 1);      \
            gload_lds4(xc0 + n, (BUF) + ((4 * wv + 0) << 8) + (t << 6));   \
            gload_lds4(xc1 + n, (BUF) + ((4 * wv + 1) << 8) + (t << 6));   \
            gload_lds4(xc2 + n, (BUF) + ((4 * wv + 2) << 8) + (t << 6));   \
            gload_lds4(xc3 + n, (BUF) + ((4 * wv + 3) << 8) + (t << 6));   \
        }                                                                  \
    }

// 256 FMAs per chunk-half: 16 ds_read_b128, weight regs WC[0..3] (static).
#define COMPUTE(BUF, WC)                                                   \
    {                                                                      \
        const float4* xb = (const float4*)(BUF);                           \
        _Pragma("unroll")                                                  \
        for (int b = 0; b < 16; ++b) {                                     \
            const float4 xv = xb[(b << 6) + lane];                         \
            _Pragma("unroll")                                              \
            for (int j = 0; j < 4; ++j) {                                  \
                acc[b][j] += xv.x * WC[j].x;                               \
                acc[b][j] += xv.y * WC[j].y;                               \
                acc[b][j] += xv.z * WC[j].z;                               \
                acc[b][j] += xv.w * WC[j].w;                               \
            }                                                              \
        }                                                                  \
    }

// Block: 256 threads = 4 waves, each wave 4 o-rows (16/block), ONE channel,
// 16 chunks of 256. Grid = 8 ot * 128 ci = 1024 = 4 blocks/CU, one pass.
// bk%8==ci%8: the 8 ot-siblings sharing a channel land on one XCD.
// __launch_bounds__(256,2): empirical hipcc VGPR cap = 256/arg = 128.
__global__ __launch_bounds__(256, 2)
void conv_fft_dot_kernel(const float* __restrict__ x, const float* __restrict__ w,
                         float* __restrict__ out) {
    // 32 KB total: two 16KB x-buffers; epilogue (64 rows * 68) overlays buf0.
    __shared__ float lds[8192];

    const int tid   = threadIdx.x;
    const int lane  = tid & 63;
    const int wv    = __builtin_amdgcn_readfirstlane(tid >> 6);
    const int bk    = blockIdx.x;
    const int ot    = bk >> 7;     // 0..7
    const int ci    = bk & 127;    // input channel
    const int obase = ot * 16 + wv * 4;

    // wave-uniform bases (SGPR): per-lane part stays a shared 32-bit offset
    const float* xc0 = x + (((4 * wv + 0) * CIN_ + ci) << 12);
    const float* xc1 = x + (((4 * wv + 1) * CIN_ + ci) << 12);
    const float* xc2 = x + (((4 * wv + 2) * CIN_ + ci) << 12);
    const float* xc3 = x + (((4 * wv + 3) * CIN_ + ci) << 12);
    const float* wr0 = w + (((obase + 0) * CIN_ + ci) << 12);
    const float* wr1 = w + (((obase + 1) * CIN_ + ci) << 12);
    const float* wr2 = w + (((obase + 2) * CIN_ + ci) << 12);
    const float* wr3 = w + (((obase + 3) * CIN_ + ci) << 12);
    const int lo = lane << 2;   // float offset of this lane's float4 in a chunk

    float acc[16][4];
#pragma unroll
    for (int b = 0; b < 16; ++b)
#pragma unroll
        for (int j = 0; j < 4; ++j) acc[b][j] = 0.f;

    f32x4 wcA[4], wcB[4];

    // ---- prologue: stage chunk 0, then chunk-0 weights (the 4 newest vm ops)
    STAGE(lds, 0)
    __builtin_amdgcn_sched_barrier(0);           // stage strictly before weights
    wcA[0] = ntload4(wr0 + lo); wcA[1] = ntload4(wr1 + lo);
    wcA[2] = ntload4(wr2 + lo); wcA[3] = ntload4(wr3 + lo);
    asm volatile("s_waitcnt vmcnt(4)" ::: "memory");  // drain stage(0), keep wcA
    __builtin_amdgcn_s_barrier();
    __builtin_amdgcn_sched_barrier(0);

    // ---- 16 chunks, 2-phase unrolled: even->buf0/wcA, odd->buf1/wcB.
#pragma unroll 1
    for (int qq = 0; qq < 16; qq += 2) {
        {   // even phase q = qq (q <= 14: always prefetches q+1)
            const int m0 = qq << 8;
            STAGE(lds + 4096, m0 + 256)
            __builtin_amdgcn_sched_barrier(0);   // stage before weight loads
            wcB[0] = ntload4(wr0 + m0 + 256 + lo);
            wcB[1] = ntload4(wr1 + m0 + 256 + lo);
            wcB[2] = ntload4(wr2 + m0 + 256 + lo);
            wcB[3] = ntload4(wr3 + m0 + 256 + lo);
            __builtin_amdgcn_sched_barrier(0);   // loads issued before compute
            COMPUTE(lds, wcA)
            asm volatile("s_waitcnt vmcnt(4)" ::: "memory");  // drain stage, keep wcB
            __builtin_amdgcn_s_barrier();
            __builtin_amdgcn_sched_barrier(0);
        }
        {   // odd phase q = qq+1 (skips prefetch when q == 15)
            const int q  = qq + 1;
            const int m0 = q << 8;
            if (q < 15) {
                STAGE(lds, m0 + 256)
                __builtin_amdgcn_sched_barrier(0);
                wcA[0] = ntload4(wr0 + m0 + 256 + lo);
                wcA[1] = ntload4(wr1 + m0 + 256 + lo);
                wcA[2] = ntload4(wr2 + m0 + 256 + lo);
                wcA[3] = ntload4(wr3 + m0 + 256 + lo);
            }
            __builtin_amdgcn_sched_barrier(0);
            COMPUTE(lds + 4096, wcB)
            if (q < 15) {
                asm volatile("s_waitcnt vmcnt(4)" ::: "memory");
                __builtin_amdgcn_s_barrier();
                __builtin_amdgcn_sched_barrier(0);
            }
        }
    }

    // ---- epilogue: cross-lane sum via padded LDS transpose in the dead
    // x-buffer (64 rows * 68 floats = 17KB <= 32KB). 4 fully-static passes
    // (rule #20: every acc index compile-time).
    __syncthreads();
#pragma unroll
    for (int p = 0; p < 4; ++p) {
        if (p) __syncthreads();
#pragma unroll
        for (int bb = 0; bb < 4; ++bb)
#pragma unroll
            for (int j = 0; j < 4; ++j)
                lds[(wv * 16 + bb * 4 + j) * 68 + lane] = acc[p * 4 + bb][j];
        __syncthreads();
        if (tid < 64) {
            const float4* row = (const float4*)(lds + tid * 68);  // 272B: 16B-aligned
            float sum = 0.f;
#pragma unroll
            for (int l = 0; l < 16; ++l) {
                const float4 v = row[l];
                sum += v.x + v.y + v.z + v.w;
            }
            const int o = ot * 16 + (tid >> 4) * 4 + (tid & 3);
            const int b = p * 4 + ((tid >> 2) & 3);
            atomicAdd(out + b * COUT_ + o, sum);
        }
    }
}

extern "C" void kernel_launch(void* const* d_in, const int* in_sizes, int n_in,
                              void* d_out, int out_size, void* d_ws, size_t ws_size,
                              hipStream_t stream) {
    const float* x    = (const float*)d_in[0];   // [16,128,4096]
    const float* wgt  = (const float*)d_in[1];   // [128,128,4096]
    const float* bias = (const float*)d_in[2];   // [128]
    float* out = (float*)d_out;                  // [16,128,1]
    (void)in_sizes; (void)n_in; (void)d_ws; (void)ws_size; (void)out_size;

    init_out_kernel<<<8, 256, 0, stream>>>(bias, out);
    conv_fft_dot_kernel<<<1024, 256, 0, stream>>>(x, wgt, out);
}